// Round 9
// baseline (188.773 us; speedup 1.0000x reference)
//
#include <hip/hip_runtime.h>
#include <hip/hip_bf16.h>

typedef unsigned short ushort_t;
typedef unsigned int uint_t;

#define DIM   256
#define LSEQ  32768
#define HEADS 8
#define CPG   8
#define EPS   1e-5f

typedef float f32x4 __attribute__((ext_vector_type(4)));
typedef float f32x16 __attribute__((ext_vector_type(16)));
typedef short sfrag8 __attribute__((ext_vector_type(8)));

static __device__ __forceinline__ ushort_t f2bs(float f) {
    union { __hip_bfloat16 h; ushort_t u; } cv;
    cv.h = __float2bfloat16(f);
    return cv.u;
}
static __device__ __forceinline__ uint_t pk2(float a, float b) {
    return (uint_t)f2bs(a) | ((uint_t)f2bs(b) << 16);
}
static __device__ __forceinline__ void glds16(const ushort_t* g, ushort_t* l) {
    __builtin_amdgcn_global_load_lds((const __attribute__((address_space(1))) uint_t*)g,
                                     (__attribute__((address_space(3))) uint_t*)l, 16, 0, 0);
}

// ============ fused transpose + group stats: pure-register 4x4 micro-transpose ============
__global__ __launch_bounds__(256) void k_tr(const float* __restrict__ x,
                                            ushort_t* __restrict__ XT,
                                            float* __restrict__ gsum,
                                            float* __restrict__ gsumsq) {
    const int tid   = threadIdx.x;
    const int lane  = tid & 63;
    const int wv    = tid >> 6;
    const int l_blk = lane >> 3;
    const int c_blk = lane & 7;
    const int c0    = (blockIdx.x & 1) * 128;
    const int l0b   = (blockIdx.x >> 1) * 128;
    const int cb    = c0 + 32 * wv + 4 * c_blk;

    const float* xr0 = x + (size_t)(cb + 0) * LSEQ;
    const float* xr1 = x + (size_t)(cb + 1) * LSEQ;
    const float* xr2 = x + (size_t)(cb + 2) * LSEQ;
    const float* xr3 = x + (size_t)(cb + 3) * LSEQ;

    float s = 0.f, s2 = 0.f;

    #pragma unroll
    for (int t = 0; t < 4; t++) {
        const int l = l0b + 32 * t + 4 * l_blk;
        float4 a = *(const float4*)(xr0 + l);
        float4 b = *(const float4*)(xr1 + l);
        float4 c = *(const float4*)(xr2 + l);
        float4 d = *(const float4*)(xr3 + l);

        s  += (a.x + a.y + a.z + a.w) + (b.x + b.y + b.z + b.w)
            + (c.x + c.y + c.z + c.w) + (d.x + d.y + d.z + d.w);
        s2 += (a.x*a.x + a.y*a.y + a.z*a.z + a.w*a.w)
            + (b.x*b.x + b.y*b.y + b.z*b.z + b.w*b.w)
            + (c.x*c.x + c.y*c.y + c.z*c.z + c.w*c.w)
            + (d.x*d.x + d.y*d.y + d.z*d.z + d.w*d.w);

        ushort_t* dst = XT + (size_t)l * 256 + cb;
        uint2 p0; p0.x = pk2(a.x, b.x); p0.y = pk2(c.x, d.x);
        uint2 p1; p1.x = pk2(a.y, b.y); p1.y = pk2(c.y, d.y);
        uint2 p2; p2.x = pk2(a.z, b.z); p2.y = pk2(c.z, d.z);
        uint2 p3; p3.x = pk2(a.w, b.w); p3.y = pk2(c.w, d.w);
        *(uint2*)(dst)           = p0;
        *(uint2*)(dst + 256)     = p1;
        *(uint2*)(dst + 512)     = p2;
        *(uint2*)(dst + 768)     = p3;
    }

    s  += __shfl_xor(s, 1);   s2 += __shfl_xor(s2, 1);
    s  += __shfl_xor(s, 8);   s2 += __shfl_xor(s2, 8);
    s  += __shfl_xor(s, 16);  s2 += __shfl_xor(s2, 16);
    s  += __shfl_xor(s, 32);  s2 += __shfl_xor(s2, 32);
    if (l_blk == 0 && (c_blk & 1) == 0) {
        int g = ((c0 + 32 * wv) >> 3) + (c_blk >> 1);
        atomicAdd(&gsum[g], s);
        atomicAdd(&gsumsq[g], s2);
    }
}

// ============ fused fold: A/BB recompute + BE (all 1536 rows) + WEB/BE2 (k/v rows)
//              + S/Z zeroing (blocks 0..129) ============
__global__ __launch_bounds__(256) void k_fold(const float* __restrict__ gn_w,
                                              const float* __restrict__ gn_b,
                                              const float* __restrict__ gsum,
                                              const float* __restrict__ gsumsq,
                                              const float* __restrict__ w_qkv,
                                              const float* __restrict__ b_qkv,
                                              ushort_t* __restrict__ WEB,
                                              float* __restrict__ BE,
                                              float* __restrict__ BE2,
                                              float* __restrict__ S,
                                              float* __restrict__ Z) {
    const int r = blockIdx.x;      // 1536 qkv rows
    const int c = threadIdx.x;     // 256 channels

    // zero S (32768 f, blocks 0..127) and Z (512 f, blocks 128..129)
    if (r < 128)      S[r * 256 + c] = 0.f;
    else if (r < 130) Z[(r - 128) * 256 + c] = 0.f;

    // per-thread groupnorm fold coefficients
    const int g = c >> 3;
    const float inv_n = 1.f / (float)(CPG * LSEQ);
    float mu  = gsum[g] * inv_n;
    float var = gsumsq[g] * inv_n - mu * mu;
    float a  = gn_w[c] * rsqrtf(var + EPS);
    float bb = gn_b[c] - mu * a;

    float w = w_qkv[(size_t)r * 256 + c];

    __shared__ float red[256];
    red[c] = w * bb;
    __syncthreads();
    for (int off = 128; off > 0; off >>= 1) {
        if (c < off) red[c] += red[c + off];
        __syncthreads();
    }
    float be = b_qkv[r] + red[0];
    if (c == 0) BE[r] = be;

    if (r >= 512) {   // k/v rows -> folded bf16 weights in attn layout
        int tt = r - 512;
        int part = tt >> 9, h = (tt >> 6) & 7, j = tt & 63;
        int rp = h * 128 + part * 64 + j;
        WEB[(size_t)rp * 256 + c] = f2bs(w * a);
        if (c == 0) BE2[rp] = be;
    }
}

// ============ fused kv-GEMM + exp + context GEMM (v9: 2-wave 32x32x16 MFMA) ============
// grid 512 x 128 threads (2 waves). h = bid>>6, superchunk = bid&63 (512 cols, 16 chunks
// of 32). Wave 0 owns ALL 64 K channels -> ek; wave 1 owns all 64 V channels -> vv.
// This halves the GEMM1 LDS re-read: only 2 waves read the staged x-tile (r8 established
// k_attn is LDS-pipe/serialization-bound, not TLP-bound -- 3 blocks/CU == 2 blocks/CU).
// MFMA = 32x32x16 (m74/m101-verified layouts). Swapped operands: acc = mfma(xfrag, Wfrag):
// C/D col = wc = lane&31 (+wt*32), rows = seq = (reg&3)+8*(reg>>2)+4*(lane>>5) -> 4
// consecutive seq per reg-quad -> packed ds_write_b64 ek/vv (kept from v6).
// Af[2][16] = 128 VGPRs: __launch_bounds__(128,2) gives a hard 256-VGPR ceiling so the
// allocator can keep them resident (r2/r6 failures were implicit-bound allocations).
// Staging: global_load_lds w16 direct, dbuf, source-granule XOR-swizzle (g ^ (row&7));
// counted vmcnt(8) one iter deep; never vmcnt(0) on fresh loads.
__global__ __launch_bounds__(128, 2) void k_attn(const ushort_t* __restrict__ XT,
                                                 const ushort_t* __restrict__ WEB,
                                                 const float* __restrict__ BE2,
                                                 float* __restrict__ S, float* __restrict__ Z) {
    __shared__ __align__(16) ushort_t xs[2][32 * 256];
    __shared__ __align__(16) ushort_t ek[64 * 40];
    __shared__ __align__(16) ushort_t vv[64 * 40];
    const int tid  = threadIdx.x;
    const int lane = tid & 63;
    const int wv   = __builtin_amdgcn_readfirstlane(tid >> 6);   // 0: K->ek, 1: V->vv
    const int l31  = lane & 31;
    const int hi   = lane >> 5;
    const int h    = blockIdx.x >> 6;
    const int cg0  = (blockIdx.x & 63) * 512;

    // Af[wt][kk]: B-operand frag (weights). wc = wv*64 + wt*32 + l31; k = kk*16 + hi*8 + e
    sfrag8 Af[2][16];
    #pragma unroll
    for (int wt = 0; wt < 2; wt++) {
        const ushort_t* ap = WEB + (size_t)(h*128 + wv*64 + wt*32 + l31) * 256 + hi*8;
        #pragma unroll
        for (int kk = 0; kk < 16; kk++) Af[wt][kk] = *(const sfrag8*)(ap + kk*16);
    }
    float bias2[2];
    #pragma unroll
    for (int wt = 0; wt < 2; wt++)
        bias2[wt] = BE2[h*128 + wv*64 + wt*32 + l31];

    f32x16 Sacc[2];
    #pragma unroll
    for (int nt = 0; nt < 2; nt++)
        #pragma unroll
        for (int e = 0; e < 16; e++) Sacc[nt][e] = 0.f;
    float zp[2];
    zp[0] = 0.f; zp[1] = 0.f;

    // prologue: stage chunk 0 (32 rows; wave stages 16 rows, 8 glds16/thread)
    #pragma unroll
    for (int kk2 = 0; kk2 < 8; kk2++) {
        const int row = wv*16 + kk2*2 + hi;
        glds16(XT + (size_t)(cg0 + row) * 256 + ((l31 ^ (row & 7)) << 3),
               &xs[0][(wv*16 + kk2*2) * 256]);
    }

    for (int t = 0; t < 16; t++) {
        const ushort_t* xb = xs[t & 1];

        if (t < 15) {
            const int l0n = cg0 + (t + 1) * 32;
            #pragma unroll
            for (int kk2 = 0; kk2 < 8; kk2++) {
                const int row = wv*16 + kk2*2 + hi;
                glds16(XT + (size_t)(l0n + row) * 256 + ((l31 ^ (row & 7)) << 3),
                       &xs[(t + 1) & 1][(wv*16 + kk2*2) * 256]);
            }
            asm volatile("s_waitcnt vmcnt(8) lgkmcnt(0)" ::: "memory");
        } else {
            asm volatile("s_waitcnt vmcnt(0) lgkmcnt(0)" ::: "memory");
        }
        __builtin_amdgcn_s_barrier();   // X: xs[t&1] staged; prev GEMM2 reads drained

        // GEMM1 (swapped, 32x32x16): A = xfrag (seq=l31 row, k=kk*16+hi*8+e), B = Af.
        // acc[wt]: col wc = wt*32+l31, rows = 32 seq.
        f32x16 acc[2];
        #pragma unroll
        for (int wt = 0; wt < 2; wt++)
            #pragma unroll
            for (int e = 0; e < 16; e++) acc[wt][e] = 0.f;

        __builtin_amdgcn_s_setprio(1);
        #pragma unroll
        for (int kk = 0; kk < 16; kk++) {
            sfrag8 a = *(const sfrag8*)&xb[l31 * 256 + (((kk*2 + hi) ^ (l31 & 7)) << 3)];
            acc[0] = __builtin_amdgcn_mfma_f32_32x32x16_bf16(a, Af[0][kk], acc[0], 0, 0, 0);
            acc[1] = __builtin_amdgcn_mfma_f32_32x32x16_bf16(a, Af[1][kk], acc[1], 0, 0, 0);
        }
        __builtin_amdgcn_s_setprio(0);

        // packed b64 writes: reg-quad g holds 4 consecutive seq (8g + 4hi + 0..3)
        // at row wc = wt*32 + l31
        if (wv == 0) {
            #pragma unroll
            for (int wt = 0; wt < 2; wt++)
                #pragma unroll
                for (int g = 0; g < 4; g++) {
                    float e0 = __expf(acc[wt][g*4+0] + bias2[wt]);
                    float e1 = __expf(acc[wt][g*4+1] + bias2[wt]);
                    float e2 = __expf(acc[wt][g*4+2] + bias2[wt]);
                    float e3 = __expf(acc[wt][g*4+3] + bias2[wt]);
                    zp[wt] += (e0 + e1) + (e2 + e3);
                    uint2 p; p.x = pk2(e0, e1); p.y = pk2(e2, e3);
                    *(uint2*)&ek[(wt*32 + l31) * 40 + g*8 + hi*4] = p;
                }
        } else {
            #pragma unroll
            for (int wt = 0; wt < 2; wt++)
                #pragma unroll
                for (int g = 0; g < 4; g++) {
                    uint2 p;
                    p.x = pk2(acc[wt][g*4+0] + bias2[wt], acc[wt][g*4+1] + bias2[wt]);
                    p.y = pk2(acc[wt][g*4+2] + bias2[wt], acc[wt][g*4+3] + bias2[wt]);
                    *(uint2*)&vv[(wt*32 + l31) * 40 + g*8 + hi*4] = p;
                }
        }
        asm volatile("s_waitcnt lgkmcnt(0)" ::: "memory");
        __builtin_amdgcn_s_barrier();   // Y: ek/vv visible

        // GEMM2 (32x32x16): S += ek @ vv^T, K=32 (2 steps). Wave owns S rows wv*32..+32.
        __builtin_amdgcn_s_setprio(1);
        #pragma unroll
        for (int kk = 0; kk < 2; kk++) {
            sfrag8 a = *(const sfrag8*)&ek[(wv*32 + l31) * 40 + kk*16 + hi*8];
            #pragma unroll
            for (int nt = 0; nt < 2; nt++) {
                sfrag8 b = *(const sfrag8*)&vv[(nt*32 + l31) * 40 + kk*16 + hi*8];
                Sacc[nt] = __builtin_amdgcn_mfma_f32_32x32x16_bf16(a, b, Sacc[nt], 0, 0, 0);
            }
        }
        __builtin_amdgcn_s_setprio(0);
    }

    float* Sh = S + h * 4096;
    #pragma unroll
    for (int nt = 0; nt < 2; nt++)
        #pragma unroll
        for (int reg = 0; reg < 16; reg++) {
            int row = wv*32 + (reg & 3) + 8*(reg >> 2) + 4*hi;
            int col = nt*32 + l31;
            atomicAdd(&Sh[row * 64 + col], Sacc[nt][reg]);
        }

    // Z: zp[wt] sums this lane's 16 seq; pair (lane, lane^32) shares wc -> one xor.
    if (wv == 0) {
        #pragma unroll
        for (int wt = 0; wt < 2; wt++) {
            float z = zp[wt];
            z += __shfl_xor(z, 32);
            if (hi == 0)
                atomicAdd(&Z[h*64 + wt*32 + l31], z);
        }
    }
}

// ============ fused W2 (LDS) + W3B/B3: removes W2 global round-trip ============
__global__ __launch_bounds__(512) void k_w23(const float* __restrict__ w_out,
                                             const float* __restrict__ S,
                                             const float* __restrict__ Z,
                                             const float* __restrict__ w_qkv,
                                             const float* __restrict__ BE,
                                             const float* __restrict__ gn_w,
                                             const float* __restrict__ gsum,
                                             const float* __restrict__ gsumsq,
                                             const float* __restrict__ b_out,
                                             ushort_t* __restrict__ W3B,
                                             float* __restrict__ B3) {
    const int d = blockIdx.x;       // 256 output channels
    const int t = threadIdx.x;      // 512
    __shared__ float w2s[512];
    __shared__ float ps[512];
    __shared__ float red[256];

    // phase 1: W2 row d into LDS: w2s[hc] = dot(w_out[d][h64..], S[hc]) / Z[hc]
    {
        const int hc  = t;
        const int h64 = hc & ~63;
        float invZ = 1.f / Z[hc];
        const float4* wo = (const float4*)(w_out + (size_t)d * 512 + h64);
        const float4* Sr = (const float4*)(S + (size_t)hc * 64);
        float s = 0.f;
        #pragma unroll
        for (int e4 = 0; e4 < 16; e4++) {
            float4 a = wo[e4], b = Sr[e4];
            s += a.x*b.x + a.y*b.y + a.z*b.z + a.w*b.w;
        }
        w2s[hc] = s * invZ;
    }
    __syncthreads();

    // phase 2: W3B[d][c] = A[c] * sum_hc w2s[hc] * w_qkv[hc][c];  B3[d] = b_out[d] + w2s.BE
    const int c = t & 255, hf = t >> 8;
    const int h0 = hf * 256;
    float s0 = 0.f, s1 = 0.f;
    #pragma unroll 8
    for (int i = 0; i < 256; i += 2) {
        s0 += w2s[h0 + i]     * w_qkv[(size_t)(h0 + i) * 256 + c];
        s1 += w2s[h0 + i + 1] * w_qkv[(size_t)(h0 + i + 1) * 256 + c];
    }
    ps[t] = s0 + s1;
    if (hf == 0) red[c] = w2s[c] * BE[c] + w2s[256 + c] * BE[256 + c];
    __syncthreads();
    if (hf == 0) {
        const int g = c >> 3;
        const float inv_n = 1.f / (float)(CPG * LSEQ);
        float mu  = gsum[g] * inv_n;
        float var = gsumsq[g] * inv_n - mu * mu;
        float a = gn_w[c] * rsqrtf(var + EPS);
        W3B[(size_t)d * 256 + c] = f2bs((ps[c] + ps[256 + c]) * a);
    }
    for (int off = 128; off > 0; off >>= 1) {
        if (hf == 0 && c < off) red[c] += red[c + off];
        __syncthreads();
    }
    if (t == 0) B3[d] = b_out[d] + red[0];
}

// ============ final GEMM: out = W3B @ xT + b3 (glds staging + swizzle + setprio) ============
// grid 1024: m0 = (bid>>9)*128, chunk = bid&511. Wave owns 32 rows x 64 cols.
// (256,3): LDS 32KB x3 = 96KB fits; live VGPR ~130 < 170 budget.
__global__ __launch_bounds__(256, 3) void k_final(const ushort_t* __restrict__ XT,
                                                  const ushort_t* __restrict__ W3B,
                                                  const float* __restrict__ B3,
                                                  float* __restrict__ out) {
    __shared__ __align__(16) ushort_t xs[64 * 256];
    const int tid  = threadIdx.x;
    const int lane = tid & 63;
    const int wv   = __builtin_amdgcn_readfirstlane(tid >> 6);
    const int ln   = lane & 15;
    const int q    = lane >> 4;
    const int m0   = (blockIdx.x >> 9) * 128;
    const int l0   = (blockIdx.x & 511) * 64;

    const int srow = lane >> 5;
    const int sg   = lane & 31;

    // stage 64 rows via global_load_lds w16, XOR-swizzled source granules
    #pragma unroll
    for (int kk = 0; kk < 8; kk++) {
        const int row = wv*16 + kk*2 + srow;
        glds16(XT + (size_t)(l0 + row) * 256 + ((sg ^ (row & 7)) << 3),
               &xs[(wv*16 + kk*2) * 256]);
    }

    sfrag8 Af[2][8];
    #pragma unroll
    for (int mt = 0; mt < 2; mt++) {
        const ushort_t* ap = W3B + (size_t)(m0 + wv*32 + mt*16 + ln) * 256 + q*8;
        #pragma unroll
        for (int k0 = 0; k0 < 8; k0++) Af[mt][k0] = *(const sfrag8*)(ap + k0*32);
    }
    float bias[2][4];
    #pragma unroll
    for (int mt = 0; mt < 2; mt++)
        #pragma unroll
        for (int r = 0; r < 4; r++)
            bias[mt][r] = B3[m0 + wv*32 + mt*16 + q*4 + r];

    asm volatile("s_waitcnt vmcnt(0)" ::: "memory");
    __builtin_amdgcn_s_barrier();

    f32x4 acc[2][4];
    #pragma unroll
    for (int mt = 0; mt < 2; mt++)
        #pragma unroll
        for (int nt = 0; nt < 4; nt++)
            #pragma unroll
            for (int e = 0; e < 4; e++) acc[mt][nt][e] = 0.f;

    __builtin_amdgcn_s_setprio(1);
    #pragma unroll
    for (int k0 = 0; k0 < 8; k0++) {
        const int gg0 = ((k0*4 + q) ^ (ln & 7)) << 3;
        sfrag8 b0 = *(const sfrag8*)&xs[(0*16 + ln) * 256 + gg0];
        sfrag8 b1 = *(const sfrag8*)&xs[(1*16 + ln) * 256 + gg0];
        sfrag8 b2 = *(const sfrag8*)&xs[(2*16 + ln) * 256 + gg0];
        sfrag8 b3 = *(const sfrag8*)&xs[(3*16 + ln) * 256 + gg0];
        #pragma unroll
        for (int mt = 0; mt < 2; mt++) {
            acc[mt][0] = __builtin_amdgcn_mfma_f32_16x16x32_bf16(Af[mt][k0], b0, acc[mt][0], 0, 0, 0);
            acc[mt][1] = __builtin_amdgcn_mfma_f32_16x16x32_bf16(Af[mt][k0], b1, acc[mt][1], 0, 0, 0);
            acc[mt][2] = __builtin_amdgcn_mfma_f32_16x16x32_bf16(Af[mt][k0], b2, acc[mt][2], 0, 0, 0);
            acc[mt][3] = __builtin_amdgcn_mfma_f32_16x16x32_bf16(Af[mt][k0], b3, acc[mt][3], 0, 0, 0);
        }
    }
    __builtin_amdgcn_s_setprio(0);

    #pragma unroll
    for (int mt = 0; mt < 2; mt++)
        #pragma unroll
        for (int nt = 0; nt < 4; nt++)
            #pragma unroll
            for (int r = 0; r < 4; r++) {
                int row = m0 + wv*32 + mt*16 + q*4 + r;
                int col = l0 + nt*16 + ln;
                out[(size_t)row * LSEQ + col] = acc[mt][nt][r] + bias[mt][r];
            }
}

// ============ launch ============
extern "C" void kernel_launch(void* const* d_in, const int* in_sizes, int n_in,
                              void* d_out, int out_size, void* d_ws, size_t ws_size,
                              hipStream_t stream) {
    const float* x     = (const float*)d_in[0];
    const float* gn_w  = (const float*)d_in[1];
    const float* gn_b  = (const float*)d_in[2];
    const float* w_qkv = (const float*)d_in[3];
    const float* b_qkv = (const float*)d_in[4];
    const float* w_out = (const float*)d_in[5];
    const float* b_out = (const float*)d_in[6];
    float* out = (float*)d_out;
    float* ws  = (float*)d_ws;

    float*    gsum   = ws + 0;        // 32
    float*    gsumsq = ws + 32;       // 32   [memset covers 64 floats]
    float*    S      = ws + 64;       // 32768 [zeroed by k_fold]
    float*    Z      = ws + 32832;    // 512   [zeroed by k_fold]
    float*    BE     = ws + 33856;    // 1536
    float*    BE2    = ws + 35392;    // 1024
    ushort_t* WEB    = (ushort_t*)(ws + 36416);    // 1024*256 bf16 (65536 f)
    ushort_t* W3B    = (ushort_t*)(ws + 233024);   // 256*256 bf16 (32768 f)
    float*    B3     = ws + 265792;   // 256
    ushort_t* XT     = (ushort_t*)(ws + 266048);   // 32768*256 bf16 (4194304 f)

    hipMemsetAsync(ws, 0, 64 * sizeof(float), stream);   // gsum, gsumsq only
    k_tr    <<<512,  256, 0, stream>>>(x, XT, gsum, gsumsq);
    k_fold  <<<1536, 256, 0, stream>>>(gn_w, gn_b, gsum, gsumsq, w_qkv, b_qkv,
                                       WEB, BE, BE2, S, Z);
    k_attn  <<<512,  128, 0, stream>>>(XT, WEB, BE2, S, Z);
    k_w23   <<<256,  512, 0, stream>>>(w_out, S, Z, w_qkv, BE, gn_w, gsum, gsumsq,
                                       b_out, W3B, B3);
    k_final <<<1024, 256, 0, stream>>>(XT, W3B, B3, out);
}

// Round 10
// 180.264 us; speedup vs baseline: 1.0472x; 1.0472x over previous
//
#include <hip/hip_runtime.h>
#include <hip/hip_bf16.h>

typedef unsigned short ushort_t;
typedef unsigned int uint_t;

#define DIM   256
#define LSEQ  32768
#define HEADS 8
#define CPG   8
#define EPS   1e-5f

typedef float f32x4 __attribute__((ext_vector_type(4)));
typedef short sfrag8 __attribute__((ext_vector_type(8)));

static __device__ __forceinline__ ushort_t f2bs(float f) {
    union { __hip_bfloat16 h; ushort_t u; } cv;
    cv.h = __float2bfloat16(f);
    return cv.u;
}
static __device__ __forceinline__ uint_t pk2(float a, float b) {
    return (uint_t)f2bs(a) | ((uint_t)f2bs(b) << 16);
}
static __device__ __forceinline__ void glds16(const ushort_t* g, ushort_t* l) {
    __builtin_amdgcn_global_load_lds((const __attribute__((address_space(1))) uint_t*)g,
                                     (__attribute__((address_space(3))) uint_t*)l, 16, 0, 0);
}

// ============ fused transpose + group stats: pure-register 4x4 micro-transpose ============
__global__ __launch_bounds__(256) void k_tr(const float* __restrict__ x,
                                            ushort_t* __restrict__ XT,
                                            float* __restrict__ gsum,
                                            float* __restrict__ gsumsq) {
    const int tid   = threadIdx.x;
    const int lane  = tid & 63;
    const int wv    = tid >> 6;
    const int l_blk = lane >> 3;
    const int c_blk = lane & 7;
    const int c0    = (blockIdx.x & 1) * 128;
    const int l0b   = (blockIdx.x >> 1) * 128;
    const int cb    = c0 + 32 * wv + 4 * c_blk;

    const float* xr0 = x + (size_t)(cb + 0) * LSEQ;
    const float* xr1 = x + (size_t)(cb + 1) * LSEQ;
    const float* xr2 = x + (size_t)(cb + 2) * LSEQ;
    const float* xr3 = x + (size_t)(cb + 3) * LSEQ;

    float s = 0.f, s2 = 0.f;

    #pragma unroll
    for (int t = 0; t < 4; t++) {
        const int l = l0b + 32 * t + 4 * l_blk;
        float4 a = *(const float4*)(xr0 + l);
        float4 b = *(const float4*)(xr1 + l);
        float4 c = *(const float4*)(xr2 + l);
        float4 d = *(const float4*)(xr3 + l);

        s  += (a.x + a.y + a.z + a.w) + (b.x + b.y + b.z + b.w)
            + (c.x + c.y + c.z + c.w) + (d.x + d.y + d.z + d.w);
        s2 += (a.x*a.x + a.y*a.y + a.z*a.z + a.w*a.w)
            + (b.x*b.x + b.y*b.y + b.z*b.z + b.w*b.w)
            + (c.x*c.x + c.y*c.y + c.z*c.z + c.w*c.w)
            + (d.x*d.x + d.y*d.y + d.z*d.z + d.w*d.w);

        ushort_t* dst = XT + (size_t)l * 256 + cb;
        uint2 p0; p0.x = pk2(a.x, b.x); p0.y = pk2(c.x, d.x);
        uint2 p1; p1.x = pk2(a.y, b.y); p1.y = pk2(c.y, d.y);
        uint2 p2; p2.x = pk2(a.z, b.z); p2.y = pk2(c.z, d.z);
        uint2 p3; p3.x = pk2(a.w, b.w); p3.y = pk2(c.w, d.w);
        *(uint2*)(dst)           = p0;
        *(uint2*)(dst + 256)     = p1;
        *(uint2*)(dst + 512)     = p2;
        *(uint2*)(dst + 768)     = p3;
    }

    s  += __shfl_xor(s, 1);   s2 += __shfl_xor(s2, 1);
    s  += __shfl_xor(s, 8);   s2 += __shfl_xor(s2, 8);
    s  += __shfl_xor(s, 16);  s2 += __shfl_xor(s2, 16);
    s  += __shfl_xor(s, 32);  s2 += __shfl_xor(s2, 32);
    if (l_blk == 0 && (c_blk & 1) == 0) {
        int g = ((c0 + 32 * wv) >> 3) + (c_blk >> 1);
        atomicAdd(&gsum[g], s);
        atomicAdd(&gsumsq[g], s2);
    }
}

// ============ fused fold: A/BB recompute + BE (all 1536 rows) + WEB/BE2 (k/v rows)
//              + S/Z zeroing (blocks 0..129) ============
__global__ __launch_bounds__(256) void k_fold(const float* __restrict__ gn_w,
                                              const float* __restrict__ gn_b,
                                              const float* __restrict__ gsum,
                                              const float* __restrict__ gsumsq,
                                              const float* __restrict__ w_qkv,
                                              const float* __restrict__ b_qkv,
                                              ushort_t* __restrict__ WEB,
                                              float* __restrict__ BE,
                                              float* __restrict__ BE2,
                                              float* __restrict__ S,
                                              float* __restrict__ Z) {
    const int r = blockIdx.x;      // 1536 qkv rows
    const int c = threadIdx.x;     // 256 channels

    // zero S (32768 f, blocks 0..127) and Z (512 f, blocks 128..129)
    if (r < 128)      S[r * 256 + c] = 0.f;
    else if (r < 130) Z[(r - 128) * 256 + c] = 0.f;

    // per-thread groupnorm fold coefficients
    const int g = c >> 3;
    const float inv_n = 1.f / (float)(CPG * LSEQ);
    float mu  = gsum[g] * inv_n;
    float var = gsumsq[g] * inv_n - mu * mu;
    float a  = gn_w[c] * rsqrtf(var + EPS);
    float bb = gn_b[c] - mu * a;

    float w = w_qkv[(size_t)r * 256 + c];

    __shared__ float red[256];
    red[c] = w * bb;
    __syncthreads();
    for (int off = 128; off > 0; off >>= 1) {
        if (c < off) red[c] += red[c + off];
        __syncthreads();
    }
    float be = b_qkv[r] + red[0];
    if (c == 0) BE[r] = be;

    if (r >= 512) {   // k/v rows -> folded bf16 weights in attn layout
        int tt = r - 512;
        int part = tt >> 9, h = (tt >> 6) & 7, j = tt & 63;
        int rp = h * 128 + part * 64 + j;
        WEB[(size_t)rp * 256 + c] = f2bs(w * a);
        if (c == 0) BE2[rp] = be;
    }
}

// ============ fused kv-GEMM + exp + context GEMM (v10: 1-barrier pipelined GEMM2) ============
// grid 512 x 256 threads (4 waves). h = bid>>6, superchunk = bid&63 (512 cols, 16 chunks
// of 32). Wave wv: mh=wv>>1 (0: K rows -> ek, 1: V rows -> vv), ms=(wv&1)*32.
// Compute is bit-identical to v6 (swapped-operand GEMM1, packed b64 ek/vv writes,
// Af[2][8]=64 VGPR -- the r2/r6/r9-established allocator residency cap).
// NEW: ek/vv double-buffered and GEMM2 runs ONE CHUNK BEHIND -> one barrier per chunk
// (17 vs 32). Phase t: {vmcnt(0)+lgkm(0) drain, barrier, issue stage(t+1)->xs[(t+1)&1],
// GEMM1(t) from xs[t&1], write ekvv[t&1], GEMM2(t-1) from ekvv[(t-1)&1]}.
// Hazards: stage(t+1) vs GEMM1(t-1) reads of same xs buffer -> separated by barrier_t;
// ekvv write[t&1] vs GEMM2 read[(t-1)&1] -> disjoint buffers; reuse of ekvv[(t-1)&1] by
// phase t+1 writes vs GEMM2(t-1) reads -> barrier_{t+1}. Stage(t) DMA one full phase old
// at its vmcnt(0) -> not a fresh-load drain (r1/r2 lesson). LDS 52KB.
__global__ __launch_bounds__(256, 2) void k_attn(const ushort_t* __restrict__ XT,
                                                 const ushort_t* __restrict__ WEB,
                                                 const float* __restrict__ BE2,
                                                 float* __restrict__ S, float* __restrict__ Z) {
    __shared__ __align__(16) ushort_t xs[2][32 * 256];
    __shared__ __align__(16) ushort_t ek[2][64 * 40];
    __shared__ __align__(16) ushort_t vv[2][64 * 40];
    const int tid  = threadIdx.x;
    const int lane = tid & 63;
    const int wv   = __builtin_amdgcn_readfirstlane(tid >> 6);
    const int ln   = lane & 15;
    const int q    = lane >> 4;
    const int mh   = wv >> 1;
    const int ms   = (wv & 1) * 32;
    const int h    = blockIdx.x >> 6;
    const int cg0  = (blockIdx.x & 63) * 512;

    const int srow = lane >> 5;
    const int sg   = lane & 31;

    sfrag8 Af[2][8];
    #pragma unroll
    for (int mt = 0; mt < 2; mt++) {
        const ushort_t* ap = WEB + (size_t)(h*128 + mh*64 + ms + mt*16 + ln) * 256 + q*8;
        #pragma unroll
        for (int k0 = 0; k0 < 8; k0++) Af[mt][k0] = *(const sfrag8*)(ap + k0*32);
    }
    // bias indexed by weight-channel wc = wt*16+ln (swapped layout)
    float bias2[2];
    #pragma unroll
    for (int wt = 0; wt < 2; wt++)
        bias2[wt] = BE2[h*128 + mh*64 + ms + wt*16 + ln];

    f32x4 Sacc[4];
    #pragma unroll
    for (int nt = 0; nt < 4; nt++)
        #pragma unroll
        for (int e = 0; e < 4; e++) Sacc[nt][e] = 0.f;
    float zp[2];
    zp[0] = 0.f; zp[1] = 0.f;

    // prologue: stage chunk 0 into xs[0]
    #pragma unroll
    for (int kk = 0; kk < 4; kk++) {
        const int row = wv*8 + kk*2 + srow;
        glds16(XT + (size_t)(cg0 + row) * 256 + ((sg ^ (row & 7)) << 3),
               &xs[0][(wv*8 + kk*2) * 256]);
    }

    for (int t = 0; t < 16; t++) {
        // drain: stage(t) complete (one phase old), phase t-1 LDS ops done
        asm volatile("s_waitcnt vmcnt(0) lgkmcnt(0)" ::: "memory");
        __builtin_amdgcn_s_barrier();

        // issue stage of chunk t+1 (lands during this phase, waited at top of t+1)
        if (t < 15) {
            const int l0n = cg0 + (t + 1) * 32;
            #pragma unroll
            for (int kk = 0; kk < 4; kk++) {
                const int row = wv*8 + kk*2 + srow;
                glds16(XT + (size_t)(l0n + row) * 256 + ((sg ^ (row & 7)) << 3),
                       &xs[(t + 1) & 1][(wv*8 + kk*2) * 256]);
            }
        }

        const ushort_t* xb = xs[t & 1];
        ushort_t* ekw = ek[t & 1];
        ushort_t* vvw = vv[t & 1];

        // GEMM1 (swapped): acc[st][wt], D rows = seq (st*16 + q*4 + r), cols = wc (wt*16+ln)
        f32x4 acc[2][2];
        #pragma unroll
        for (int st = 0; st < 2; st++)
            #pragma unroll
            for (int wt = 0; wt < 2; wt++)
                #pragma unroll
                for (int e = 0; e < 4; e++) acc[st][wt][e] = 0.f;

        __builtin_amdgcn_s_setprio(1);
        #pragma unroll
        for (int k0 = 0; k0 < 8; k0++) {
            sfrag8 b0 = *(const sfrag8*)&xb[(0*16 + ln) * 256 + (((k0*4 + q) ^ (ln & 7)) << 3)];
            sfrag8 b1 = *(const sfrag8*)&xb[(1*16 + ln) * 256 + (((k0*4 + q) ^ (ln & 7)) << 3)];
            #pragma unroll
            for (int wt = 0; wt < 2; wt++) {
                acc[0][wt] = __builtin_amdgcn_mfma_f32_16x16x32_bf16(b0, Af[wt][k0], acc[0][wt], 0, 0, 0);
                acc[1][wt] = __builtin_amdgcn_mfma_f32_16x16x32_bf16(b1, Af[wt][k0], acc[1][wt], 0, 0, 0);
            }
        }
        __builtin_amdgcn_s_setprio(0);

        // packed b64 writes into ekvv[t&1]
        if (mh == 0) {
            #pragma unroll
            for (int st = 0; st < 2; st++)
                #pragma unroll
                for (int wt = 0; wt < 2; wt++) {
                    float e0 = __expf(acc[st][wt][0] + bias2[wt]);
                    float e1 = __expf(acc[st][wt][1] + bias2[wt]);
                    float e2 = __expf(acc[st][wt][2] + bias2[wt]);
                    float e3 = __expf(acc[st][wt][3] + bias2[wt]);
                    zp[wt] += (e0 + e1) + (e2 + e3);
                    uint2 p; p.x = pk2(e0, e1); p.y = pk2(e2, e3);
                    *(uint2*)&ekw[(ms + wt*16 + ln) * 40 + st*16 + q*4] = p;
                }
        } else {
            #pragma unroll
            for (int st = 0; st < 2; st++)
                #pragma unroll
                for (int wt = 0; wt < 2; wt++) {
                    uint2 p;
                    p.x = pk2(acc[st][wt][0] + bias2[wt], acc[st][wt][1] + bias2[wt]);
                    p.y = pk2(acc[st][wt][2] + bias2[wt], acc[st][wt][3] + bias2[wt]);
                    *(uint2*)&vvw[(ms + wt*16 + ln) * 40 + st*16 + q*4] = p;
                }
        }

        // GEMM2 of chunk t-1 from ekvv[(t-1)&1] (written phase t-1, fenced by barrier_t)
        if (t > 0) {
            const ushort_t* ekr = ek[(t - 1) & 1];
            const ushort_t* vvr = vv[(t - 1) & 1];
            sfrag8 a = *(const sfrag8*)&ekr[(wv*16 + ln) * 40 + q*8];
            __builtin_amdgcn_s_setprio(1);
            #pragma unroll
            for (int nt = 0; nt < 4; nt++) {
                sfrag8 b = *(const sfrag8*)&vvr[(nt*16 + ln) * 40 + q*8];
                Sacc[nt] = __builtin_amdgcn_mfma_f32_16x16x32_bf16(a, b, Sacc[nt], 0, 0, 0);
            }
            __builtin_amdgcn_s_setprio(0);
        }
    }

    // epilogue: GEMM2 of chunk 15 (ekvv[1])
    asm volatile("s_waitcnt lgkmcnt(0)" ::: "memory");
    __builtin_amdgcn_s_barrier();
    {
        const ushort_t* ekr = ek[15 & 1];
        const ushort_t* vvr = vv[15 & 1];
        sfrag8 a = *(const sfrag8*)&ekr[(wv*16 + ln) * 40 + q*8];
        #pragma unroll
        for (int nt = 0; nt < 4; nt++) {
            sfrag8 b = *(const sfrag8*)&vvr[(nt*16 + ln) * 40 + q*8];
            Sacc[nt] = __builtin_amdgcn_mfma_f32_16x16x32_bf16(a, b, Sacc[nt], 0, 0, 0);
        }
    }

    float* Sh = S + h * 4096;
    #pragma unroll
    for (int nt = 0; nt < 4; nt++)
        #pragma unroll
        for (int r = 0; r < 4; r++)
            atomicAdd(&Sh[(wv*16 + q*4 + r) * 64 + nt*16 + ln], Sacc[nt][r]);

    // Z: zp[wt] is full seq-sum for kc = ms + wt*16 + ln within this wave's q-slice;
    // reduce across q-groups (lanes with same ln), then lanes 0..15 write.
    if (mh == 0) {
        #pragma unroll
        for (int wt = 0; wt < 2; wt++) {
            float z = zp[wt];
            z += __shfl_xor(z, 16);
            z += __shfl_xor(z, 32);
            if (lane < 16)
                atomicAdd(&Z[h*64 + ms + wt*16 + ln], z);
        }
    }
}

// ============ fused W2 (LDS) + W3B/B3: removes W2 global round-trip ============
__global__ __launch_bounds__(512) void k_w23(const float* __restrict__ w_out,
                                             const float* __restrict__ S,
                                             const float* __restrict__ Z,
                                             const float* __restrict__ w_qkv,
                                             const float* __restrict__ BE,
                                             const float* __restrict__ gn_w,
                                             const float* __restrict__ gsum,
                                             const float* __restrict__ gsumsq,
                                             const float* __restrict__ b_out,
                                             ushort_t* __restrict__ W3B,
                                             float* __restrict__ B3) {
    const int d = blockIdx.x;       // 256 output channels
    const int t = threadIdx.x;      // 512
    __shared__ float w2s[512];
    __shared__ float ps[512];
    __shared__ float red[256];

    // phase 1: W2 row d into LDS: w2s[hc] = dot(w_out[d][h64..], S[hc]) / Z[hc]
    {
        const int hc  = t;
        const int h64 = hc & ~63;
        float invZ = 1.f / Z[hc];
        const float4* wo = (const float4*)(w_out + (size_t)d * 512 + h64);
        const float4* Sr = (const float4*)(S + (size_t)hc * 64);
        float s = 0.f;
        #pragma unroll
        for (int e4 = 0; e4 < 16; e4++) {
            float4 a = wo[e4], b = Sr[e4];
            s += a.x*b.x + a.y*b.y + a.z*b.z + a.w*b.w;
        }
        w2s[hc] = s * invZ;
    }
    __syncthreads();

    // phase 2: W3B[d][c] = A[c] * sum_hc w2s[hc] * w_qkv[hc][c];  B3[d] = b_out[d] + w2s.BE
    const int c = t & 255, hf = t >> 8;
    const int h0 = hf * 256;
    float s0 = 0.f, s1 = 0.f;
    #pragma unroll 8
    for (int i = 0; i < 256; i += 2) {
        s0 += w2s[h0 + i]     * w_qkv[(size_t)(h0 + i) * 256 + c];
        s1 += w2s[h0 + i + 1] * w_qkv[(size_t)(h0 + i + 1) * 256 + c];
    }
    ps[t] = s0 + s1;
    if (hf == 0) red[c] = w2s[c] * BE[c] + w2s[256 + c] * BE[256 + c];
    __syncthreads();
    if (hf == 0) {
        const int g = c >> 3;
        const float inv_n = 1.f / (float)(CPG * LSEQ);
        float mu  = gsum[g] * inv_n;
        float var = gsumsq[g] * inv_n - mu * mu;
        float a = gn_w[c] * rsqrtf(var + EPS);
        W3B[(size_t)d * 256 + c] = f2bs((ps[c] + ps[256 + c]) * a);
    }
    for (int off = 128; off > 0; off >>= 1) {
        if (hf == 0 && c < off) red[c] += red[c + off];
        __syncthreads();
    }
    if (t == 0) B3[d] = b_out[d] + red[0];
}

// ============ final GEMM: out = W3B @ xT + b3 (glds staging + swizzle + setprio) ============
// grid 1024: m0 = (bid>>9)*128, chunk = bid&511. Wave owns 32 rows x 64 cols.
__global__ __launch_bounds__(256, 2) void k_final(const ushort_t* __restrict__ XT,
                                                  const ushort_t* __restrict__ W3B,
                                                  const float* __restrict__ B3,
                                                  float* __restrict__ out) {
    __shared__ __align__(16) ushort_t xs[64 * 256];
    const int tid  = threadIdx.x;
    const int lane = tid & 63;
    const int wv   = __builtin_amdgcn_readfirstlane(tid >> 6);
    const int ln   = lane & 15;
    const int q    = lane >> 4;
    const int m0   = (blockIdx.x >> 9) * 128;
    const int l0   = (blockIdx.x & 511) * 64;

    const int srow = lane >> 5;
    const int sg   = lane & 31;

    // stage 64 rows via global_load_lds w16, XOR-swizzled source granules
    #pragma unroll
    for (int kk = 0; kk < 8; kk++) {
        const int row = wv*16 + kk*2 + srow;
        glds16(XT + (size_t)(l0 + row) * 256 + ((sg ^ (row & 7)) << 3),
               &xs[(wv*16 + kk*2) * 256]);
    }

    sfrag8 Af[2][8];
    #pragma unroll
    for (int mt = 0; mt < 2; mt++) {
        const ushort_t* ap = W3B + (size_t)(m0 + wv*32 + mt*16 + ln) * 256 + q*8;
        #pragma unroll
        for (int k0 = 0; k0 < 8; k0++) Af[mt][k0] = *(const sfrag8*)(ap + k0*32);
    }
    float bias[2][4];
    #pragma unroll
    for (int mt = 0; mt < 2; mt++)
        #pragma unroll
        for (int r = 0; r < 4; r++)
            bias[mt][r] = B3[m0 + wv*32 + mt*16 + q*4 + r];

    asm volatile("s_waitcnt vmcnt(0)" ::: "memory");
    __builtin_amdgcn_s_barrier();

    f32x4 acc[2][4];
    #pragma unroll
    for (int mt = 0; mt < 2; mt++)
        #pragma unroll
        for (int nt = 0; nt < 4; nt++)
            #pragma unroll
            for (int e = 0; e < 4; e++) acc[mt][nt][e] = 0.f;

    __builtin_amdgcn_s_setprio(1);
    #pragma unroll
    for (int k0 = 0; k0 < 8; k0++) {
        const int gg0 = ((k0*4 + q) ^ (ln & 7)) << 3;
        sfrag8 b0 = *(const sfrag8*)&xs[(0*16 + ln) * 256 + gg0];
        sfrag8 b1 = *(const sfrag8*)&xs[(1*16 + ln) * 256 + gg0];
        sfrag8 b2 = *(const sfrag8*)&xs[(2*16 + ln) * 256 + gg0];
        sfrag8 b3 = *(const sfrag8*)&xs[(3*16 + ln) * 256 + gg0];
        #pragma unroll
        for (int mt = 0; mt < 2; mt++) {
            acc[mt][0] = __builtin_amdgcn_mfma_f32_16x16x32_bf16(Af[mt][k0], b0, acc[mt][0], 0, 0, 0);
            acc[mt][1] = __builtin_amdgcn_mfma_f32_16x16x32_bf16(Af[mt][k0], b1, acc[mt][1], 0, 0, 0);
            acc[mt][2] = __builtin_amdgcn_mfma_f32_16x16x32_bf16(Af[mt][k0], b2, acc[mt][2], 0, 0, 0);
            acc[mt][3] = __builtin_amdgcn_mfma_f32_16x16x32_bf16(Af[mt][k0], b3, acc[mt][3], 0, 0, 0);
        }
    }
    __builtin_amdgcn_s_setprio(0);

    #pragma unroll
    for (int mt = 0; mt < 2; mt++)
        #pragma unroll
        for (int nt = 0; nt < 4; nt++)
            #pragma unroll
            for (int r = 0; r < 4; r++) {
                int row = m0 + wv*32 + mt*16 + q*4 + r;
                int col = l0 + nt*16 + ln;
                out[(size_t)row * LSEQ + col] = acc[mt][nt][r] + bias[mt][r];
            }
}

// ============ launch ============
extern "C" void kernel_launch(void* const* d_in, const int* in_sizes, int n_in,
                              void* d_out, int out_size, void* d_ws, size_t ws_size,
                              hipStream_t stream) {
    const float* x     = (const float*)d_in[0];
    const float* gn_w  = (const float*)d_in[1];
    const float* gn_b  = (const float*)d_in[2];
    const float* w_qkv = (const float*)d_in[3];
    const float* b_qkv = (const float*)d_in[4];
    const float* w_out = (const float*)d_in[5];
    const float* b_out = (const float*)d_in[6];
    float* out = (float*)d_out;
    float* ws  = (float*)d_ws;

    float*    gsum   = ws + 0;        // 32
    float*    gsumsq = ws + 32;       // 32   [memset covers 64 floats]
    float*    S      = ws + 64;       // 32768 [zeroed by k_fold]
    float*    Z      = ws + 32832;    // 512   [zeroed by k_fold]
    float*    BE     = ws + 33856;    // 1536
    float*    BE2    = ws + 35392;    // 1024
    ushort_t* WEB    = (ushort_t*)(ws + 36416);    // 1024*256 bf16 (65536 f)
    ushort_t* W3B    = (ushort_t*)(ws + 233024);   // 256*256 bf16 (32768 f)
    float*    B3     = ws + 265792;   // 256
    ushort_t* XT     = (ushort_t*)(ws + 266048);   // 32768*256 bf16 (4194304 f)

    hipMemsetAsync(ws, 0, 64 * sizeof(float), stream);   // gsum, gsumsq only
    k_tr    <<<512,  256, 0, stream>>>(x, XT, gsum, gsumsq);
    k_fold  <<<1536, 256, 0, stream>>>(gn_w, gn_b, gsum, gsumsq, w_qkv, b_qkv,
                                       WEB, BE, BE2, S, Z);
    k_attn  <<<512,  256, 0, stream>>>(XT, WEB, BE2, S, Z);
    k_w23   <<<256,  512, 0, stream>>>(w_out, S, Z, w_qkv, BE, gn_w, gsum, gsumsq,
                                       b_out, W3B, B3);
    k_final <<<1024, 256, 0, stream>>>(XT, W3B, B3, out);
}

// Round 11
// 176.574 us; speedup vs baseline: 1.0691x; 1.0209x over previous
//
#include <hip/hip_runtime.h>
#include <hip/hip_bf16.h>

typedef unsigned short ushort_t;
typedef unsigned int uint_t;

#define DIM   256
#define LSEQ  32768
#define HEADS 8
#define CPG   8
#define EPS   1e-5f

typedef float f32x4 __attribute__((ext_vector_type(4)));
typedef short sfrag8 __attribute__((ext_vector_type(8)));

static __device__ __forceinline__ ushort_t f2bs(float f) {
    union { __hip_bfloat16 h; ushort_t u; } cv;
    cv.h = __float2bfloat16(f);
    return cv.u;
}
static __device__ __forceinline__ uint_t pk2(float a, float b) {
    return (uint_t)f2bs(a) | ((uint_t)f2bs(b) << 16);
}
static __device__ __forceinline__ void glds16(const ushort_t* g, ushort_t* l) {
    __builtin_amdgcn_global_load_lds((const __attribute__((address_space(1))) uint_t*)g,
                                     (__attribute__((address_space(3))) uint_t*)l, 16, 0, 0);
}

// ============ fused transpose + group stats: pure-register 4x4 micro-transpose ============
__global__ __launch_bounds__(256) void k_tr(const float* __restrict__ x,
                                            ushort_t* __restrict__ XT,
                                            float* __restrict__ gsum,
                                            float* __restrict__ gsumsq) {
    const int tid   = threadIdx.x;
    const int lane  = tid & 63;
    const int wv    = tid >> 6;
    const int l_blk = lane >> 3;
    const int c_blk = lane & 7;
    const int c0    = (blockIdx.x & 1) * 128;
    const int l0b   = (blockIdx.x >> 1) * 128;
    const int cb    = c0 + 32 * wv + 4 * c_blk;

    const float* xr0 = x + (size_t)(cb + 0) * LSEQ;
    const float* xr1 = x + (size_t)(cb + 1) * LSEQ;
    const float* xr2 = x + (size_t)(cb + 2) * LSEQ;
    const float* xr3 = x + (size_t)(cb + 3) * LSEQ;

    float s = 0.f, s2 = 0.f;

    #pragma unroll
    for (int t = 0; t < 4; t++) {
        const int l = l0b + 32 * t + 4 * l_blk;
        float4 a = *(const float4*)(xr0 + l);
        float4 b = *(const float4*)(xr1 + l);
        float4 c = *(const float4*)(xr2 + l);
        float4 d = *(const float4*)(xr3 + l);

        s  += (a.x + a.y + a.z + a.w) + (b.x + b.y + b.z + b.w)
            + (c.x + c.y + c.z + c.w) + (d.x + d.y + d.z + d.w);
        s2 += (a.x*a.x + a.y*a.y + a.z*a.z + a.w*a.w)
            + (b.x*b.x + b.y*b.y + b.z*b.z + b.w*b.w)
            + (c.x*c.x + c.y*c.y + c.z*c.z + c.w*c.w)
            + (d.x*d.x + d.y*d.y + d.z*d.z + d.w*d.w);

        ushort_t* dst = XT + (size_t)l * 256 + cb;
        uint2 p0; p0.x = pk2(a.x, b.x); p0.y = pk2(c.x, d.x);
        uint2 p1; p1.x = pk2(a.y, b.y); p1.y = pk2(c.y, d.y);
        uint2 p2; p2.x = pk2(a.z, b.z); p2.y = pk2(c.z, d.z);
        uint2 p3; p3.x = pk2(a.w, b.w); p3.y = pk2(c.w, d.w);
        *(uint2*)(dst)           = p0;
        *(uint2*)(dst + 256)     = p1;
        *(uint2*)(dst + 512)     = p2;
        *(uint2*)(dst + 768)     = p3;
    }

    s  += __shfl_xor(s, 1);   s2 += __shfl_xor(s2, 1);
    s  += __shfl_xor(s, 8);   s2 += __shfl_xor(s2, 8);
    s  += __shfl_xor(s, 16);  s2 += __shfl_xor(s2, 16);
    s  += __shfl_xor(s, 32);  s2 += __shfl_xor(s2, 32);
    if (l_blk == 0 && (c_blk & 1) == 0) {
        int g = ((c0 + 32 * wv) >> 3) + (c_blk >> 1);
        atomicAdd(&gsum[g], s);
        atomicAdd(&gsumsq[g], s2);
    }
}

// ============ fused fold: A/BB recompute + BE (all 1536 rows) + WEB/BE2 (k/v rows)
//              + S/Z zeroing (blocks 0..129) ============
__global__ __launch_bounds__(256) void k_fold(const float* __restrict__ gn_w,
                                              const float* __restrict__ gn_b,
                                              const float* __restrict__ gsum,
                                              const float* __restrict__ gsumsq,
                                              const float* __restrict__ w_qkv,
                                              const float* __restrict__ b_qkv,
                                              ushort_t* __restrict__ WEB,
                                              float* __restrict__ BE,
                                              float* __restrict__ BE2,
                                              float* __restrict__ S,
                                              float* __restrict__ Z) {
    const int r = blockIdx.x;      // 1536 qkv rows
    const int c = threadIdx.x;     // 256 channels

    // zero S (32768 f, blocks 0..127) and Z (512 f, blocks 128..129)
    if (r < 128)      S[r * 256 + c] = 0.f;
    else if (r < 130) Z[(r - 128) * 256 + c] = 0.f;

    // per-thread groupnorm fold coefficients
    const int g = c >> 3;
    const float inv_n = 1.f / (float)(CPG * LSEQ);
    float mu  = gsum[g] * inv_n;
    float var = gsumsq[g] * inv_n - mu * mu;
    float a  = gn_w[c] * rsqrtf(var + EPS);
    float bb = gn_b[c] - mu * a;

    float w = w_qkv[(size_t)r * 256 + c];

    __shared__ float red[256];
    red[c] = w * bb;
    __syncthreads();
    for (int off = 128; off > 0; off >>= 1) {
        if (c < off) red[c] += red[c + off];
        __syncthreads();
    }
    float be = b_qkv[r] + red[0];
    if (c == 0) BE[r] = be;

    if (r >= 512) {   // k/v rows -> folded bf16 weights in attn layout
        int tt = r - 512;
        int part = tt >> 9, h = (tt >> 6) & 7, j = tt & 63;
        int rp = h * 128 + part * 64 + j;
        WEB[(size_t)rp * 256 + c] = f2bs(w * a);
        if (c == 0) BE2[rp] = be;
    }
}

// ============ fused kv-GEMM + exp + context GEMM (v12: 64-col chunks, 8 phases) ============
// grid 512 x 256 threads (4 waves). h = bid>>6, superchunk = bid&63 (512 cols, 8 chunks
// of 64). Wave wv: mh=wv>>1 (0: K rows -> ek, 1: V rows -> vv), ms=(wv&1)*32.
// r5/r8/r10 triangulated a phase-count-invariant ~35us: occupancy, barrier count, and
// write packing were all null -> the per-phase FIXED cost (drain + 4-wave barrier
// convergence + loop-carried latency) is the standing hypothesis. v12 halves phases
// (16 -> 8) by doubling the chunk to 64 cols. LDS: single xs 32KB + ek/vv pitch-72
// 18KB = 50KB. Single-xs consequence: stage(t+1) issues after barrier B (GEMM1 reads
// fenced); its latency is covered by GEMM2 + loop-back + co-resident-block overlap.
// Phase: [vmcnt0+lgkm0; barA; GEMM1; ekvv writes; lgkm0; barB; stage(t+1); GEMM2(t)].
// ekvv single-buffer safe: GEMM2(t) reads drain at t+1 step-1 lgkm before barA(t+1);
// t+1's ekvv writes come after barA(t+1). 16 barriers total (v6 had 32).
// Af[2][8]=64 VGPR (allocator residency law, r2/r6/r9). Swapped-operand GEMM1 ->
// packed b64 ekvv writes (v6).
__global__ __launch_bounds__(256, 2) void k_attn(const ushort_t* __restrict__ XT,
                                                 const ushort_t* __restrict__ WEB,
                                                 const float* __restrict__ BE2,
                                                 float* __restrict__ S, float* __restrict__ Z) {
    __shared__ __align__(16) ushort_t xs[64 * 256];
    __shared__ __align__(16) ushort_t ek[64 * 72];
    __shared__ __align__(16) ushort_t vv[64 * 72];
    const int tid  = threadIdx.x;
    const int lane = tid & 63;
    const int wv   = __builtin_amdgcn_readfirstlane(tid >> 6);
    const int ln   = lane & 15;
    const int q    = lane >> 4;
    const int mh   = wv >> 1;
    const int ms   = (wv & 1) * 32;
    const int h    = blockIdx.x >> 6;
    const int cg0  = (blockIdx.x & 63) * 512;

    const int srow = lane >> 5;
    const int sg   = lane & 31;

    sfrag8 Af[2][8];
    #pragma unroll
    for (int mt = 0; mt < 2; mt++) {
        const ushort_t* ap = WEB + (size_t)(h*128 + mh*64 + ms + mt*16 + ln) * 256 + q*8;
        #pragma unroll
        for (int k0 = 0; k0 < 8; k0++) Af[mt][k0] = *(const sfrag8*)(ap + k0*32);
    }
    // bias indexed by weight-channel wc = wt*16+ln (swapped layout)
    float bias2[2];
    #pragma unroll
    for (int wt = 0; wt < 2; wt++)
        bias2[wt] = BE2[h*128 + mh*64 + ms + wt*16 + ln];

    f32x4 Sacc[4];
    #pragma unroll
    for (int nt = 0; nt < 4; nt++)
        #pragma unroll
        for (int e = 0; e < 4; e++) Sacc[nt][e] = 0.f;
    float zp[2];
    zp[0] = 0.f; zp[1] = 0.f;

    // prologue: stage chunk 0 (64 rows; each wave 16 rows, 8 glds16/thread)
    #pragma unroll
    for (int kk = 0; kk < 8; kk++) {
        const int row = wv*16 + kk*2 + srow;
        glds16(XT + (size_t)(cg0 + row) * 256 + ((sg ^ (row & 7)) << 3),
               &xs[(wv*16 + kk*2) * 256]);
    }

    for (int t = 0; t < 8; t++) {
        // A: stage(t) complete everywhere; prev-phase GEMM2 LDS reads drained
        asm volatile("s_waitcnt vmcnt(0) lgkmcnt(0)" ::: "memory");
        __builtin_amdgcn_s_barrier();

        // GEMM1 (swapped): acc[st][wt], D rows = seq (st*16 + q*4 + r), cols = wc
        f32x4 acc[4][2];
        #pragma unroll
        for (int st = 0; st < 4; st++)
            #pragma unroll
            for (int wt = 0; wt < 2; wt++)
                #pragma unroll
                for (int e = 0; e < 4; e++) acc[st][wt][e] = 0.f;

        __builtin_amdgcn_s_setprio(1);
        #pragma unroll
        for (int k0 = 0; k0 < 8; k0++) {
            const int gg = ((k0*4 + q) ^ (ln & 7)) << 3;
            sfrag8 b0 = *(const sfrag8*)&xs[(0*16 + ln) * 256 + gg];
            sfrag8 b1 = *(const sfrag8*)&xs[(1*16 + ln) * 256 + gg];
            sfrag8 b2 = *(const sfrag8*)&xs[(2*16 + ln) * 256 + gg];
            sfrag8 b3 = *(const sfrag8*)&xs[(3*16 + ln) * 256 + gg];
            #pragma unroll
            for (int wt = 0; wt < 2; wt++) {
                acc[0][wt] = __builtin_amdgcn_mfma_f32_16x16x32_bf16(b0, Af[wt][k0], acc[0][wt], 0, 0, 0);
                acc[1][wt] = __builtin_amdgcn_mfma_f32_16x16x32_bf16(b1, Af[wt][k0], acc[1][wt], 0, 0, 0);
                acc[2][wt] = __builtin_amdgcn_mfma_f32_16x16x32_bf16(b2, Af[wt][k0], acc[2][wt], 0, 0, 0);
                acc[3][wt] = __builtin_amdgcn_mfma_f32_16x16x32_bf16(b3, Af[wt][k0], acc[3][wt], 0, 0, 0);
            }
        }
        __builtin_amdgcn_s_setprio(0);

        // packed b64 writes: 4 consecutive seq per lane at row kc = ms + wt*16 + ln
        if (mh == 0) {
            #pragma unroll
            for (int st = 0; st < 4; st++)
                #pragma unroll
                for (int wt = 0; wt < 2; wt++) {
                    float e0 = __expf(acc[st][wt][0] + bias2[wt]);
                    float e1 = __expf(acc[st][wt][1] + bias2[wt]);
                    float e2 = __expf(acc[st][wt][2] + bias2[wt]);
                    float e3 = __expf(acc[st][wt][3] + bias2[wt]);
                    zp[wt] += (e0 + e1) + (e2 + e3);
                    uint2 p; p.x = pk2(e0, e1); p.y = pk2(e2, e3);
                    *(uint2*)&ek[(ms + wt*16 + ln) * 72 + st*16 + q*4] = p;
                }
        } else {
            #pragma unroll
            for (int st = 0; st < 4; st++)
                #pragma unroll
                for (int wt = 0; wt < 2; wt++) {
                    uint2 p;
                    p.x = pk2(acc[st][wt][0] + bias2[wt], acc[st][wt][1] + bias2[wt]);
                    p.y = pk2(acc[st][wt][2] + bias2[wt], acc[st][wt][3] + bias2[wt]);
                    *(uint2*)&vv[(ms + wt*16 + ln) * 72 + st*16 + q*4] = p;
                }
        }
        // B: ekvv visible; all xs reads drained (safe to overwrite xs)
        asm volatile("s_waitcnt lgkmcnt(0)" ::: "memory");
        __builtin_amdgcn_s_barrier();

        // issue stage of chunk t+1 into xs (covered by GEMM2 + loop-back)
        if (t < 7) {
            const int l0n = cg0 + (t + 1) * 64;
            #pragma unroll
            for (int kk = 0; kk < 8; kk++) {
                const int row = wv*16 + kk*2 + srow;
                glds16(XT + (size_t)(l0n + row) * 256 + ((sg ^ (row & 7)) << 3),
                       &xs[(wv*16 + kk*2) * 256]);
            }
        }

        // GEMM2: S += ek @ vv^T (K=64, 2 k-steps). Wave owns S rows wv*16..+16.
        __builtin_amdgcn_s_setprio(1);
        #pragma unroll
        for (int k0 = 0; k0 < 2; k0++) {
            sfrag8 a = *(const sfrag8*)&ek[(wv*16 + ln) * 72 + k0*32 + q*8];
            #pragma unroll
            for (int nt = 0; nt < 4; nt++) {
                sfrag8 b = *(const sfrag8*)&vv[(nt*16 + ln) * 72 + k0*32 + q*8];
                Sacc[nt] = __builtin_amdgcn_mfma_f32_16x16x32_bf16(a, b, Sacc[nt], 0, 0, 0);
            }
        }
        __builtin_amdgcn_s_setprio(0);
    }

    float* Sh = S + h * 4096;
    #pragma unroll
    for (int nt = 0; nt < 4; nt++)
        #pragma unroll
        for (int r = 0; r < 4; r++)
            atomicAdd(&Sh[(wv*16 + q*4 + r) * 64 + nt*16 + ln], Sacc[nt][r]);

    // Z: zp[wt] is full seq-sum for kc = ms + wt*16 + ln within this wave's q-slice;
    // reduce across q-groups (lanes with same ln), then lanes 0..15 write.
    if (mh == 0) {
        #pragma unroll
        for (int wt = 0; wt < 2; wt++) {
            float z = zp[wt];
            z += __shfl_xor(z, 16);
            z += __shfl_xor(z, 32);
            if (lane < 16)
                atomicAdd(&Z[h*64 + ms + wt*16 + ln], z);
        }
    }
}

// ============ fused W2 (LDS) + W3B/B3: removes W2 global round-trip ============
__global__ __launch_bounds__(512) void k_w23(const float* __restrict__ w_out,
                                             const float* __restrict__ S,
                                             const float* __restrict__ Z,
                                             const float* __restrict__ w_qkv,
                                             const float* __restrict__ BE,
                                             const float* __restrict__ gn_w,
                                             const float* __restrict__ gsum,
                                             const float* __restrict__ gsumsq,
                                             const float* __restrict__ b_out,
                                             ushort_t* __restrict__ W3B,
                                             float* __restrict__ B3) {
    const int d = blockIdx.x;       // 256 output channels
    const int t = threadIdx.x;      // 512
    __shared__ float w2s[512];
    __shared__ float ps[512];
    __shared__ float red[256];

    // phase 1: W2 row d into LDS: w2s[hc] = dot(w_out[d][h64..], S[hc]) / Z[hc]
    {
        const int hc  = t;
        const int h64 = hc & ~63;
        float invZ = 1.f / Z[hc];
        const float4* wo = (const float4*)(w_out + (size_t)d * 512 + h64);
        const float4* Sr = (const float4*)(S + (size_t)hc * 64);
        float s = 0.f;
        #pragma unroll
        for (int e4 = 0; e4 < 16; e4++) {
            float4 a = wo[e4], b = Sr[e4];
            s += a.x*b.x + a.y*b.y + a.z*b.z + a.w*b.w;
        }
        w2s[hc] = s * invZ;
    }
    __syncthreads();

    // phase 2: W3B[d][c] = A[c] * sum_hc w2s[hc] * w_qkv[hc][c];  B3[d] = b_out[d] + w2s.BE
    const int c = t & 255, hf = t >> 8;
    const int h0 = hf * 256;
    float s0 = 0.f, s1 = 0.f;
    #pragma unroll 8
    for (int i = 0; i < 256; i += 2) {
        s0 += w2s[h0 + i]     * w_qkv[(size_t)(h0 + i) * 256 + c];
        s1 += w2s[h0 + i + 1] * w_qkv[(size_t)(h0 + i + 1) * 256 + c];
    }
    ps[t] = s0 + s1;
    if (hf == 0) red[c] = w2s[c] * BE[c] + w2s[256 + c] * BE[256 + c];
    __syncthreads();
    if (hf == 0) {
        const int g = c >> 3;
        const float inv_n = 1.f / (float)(CPG * LSEQ);
        float mu  = gsum[g] * inv_n;
        float var = gsumsq[g] * inv_n - mu * mu;
        float a = gn_w[c] * rsqrtf(var + EPS);
        W3B[(size_t)d * 256 + c] = f2bs((ps[c] + ps[256 + c]) * a);
    }
    for (int off = 128; off > 0; off >>= 1) {
        if (hf == 0 && c < off) red[c] += red[c + off];
        __syncthreads();
    }
    if (t == 0) B3[d] = b_out[d] + red[0];
}

// ============ final GEMM: out = W3B @ xT + b3 (glds staging + swizzle + setprio) ============
// grid 1024: m0 = (bid>>9)*128, chunk = bid&511. Wave owns 32 rows x 64 cols.
__global__ __launch_bounds__(256, 2) void k_final(const ushort_t* __restrict__ XT,
                                                  const ushort_t* __restrict__ W3B,
                                                  const float* __restrict__ B3,
                                                  float* __restrict__ out) {
    __shared__ __align__(16) ushort_t xs[64 * 256];
    const int tid  = threadIdx.x;
    const int lane = tid & 63;
    const int wv   = __builtin_amdgcn_readfirstlane(tid >> 6);
    const int ln   = lane & 15;
    const int q    = lane >> 4;
    const int m0   = (blockIdx.x >> 9) * 128;
    const int l0   = (blockIdx.x & 511) * 64;

    const int srow = lane >> 5;
    const int sg   = lane & 31;

    // stage 64 rows via global_load_lds w16, XOR-swizzled source granules
    #pragma unroll
    for (int kk = 0; kk < 8; kk++) {
        const int row = wv*16 + kk*2 + srow;
        glds16(XT + (size_t)(l0 + row) * 256 + ((sg ^ (row & 7)) << 3),
               &xs[(wv*16 + kk*2) * 256]);
    }

    sfrag8 Af[2][8];
    #pragma unroll
    for (int mt = 0; mt < 2; mt++) {
        const ushort_t* ap = W3B + (size_t)(m0 + wv*32 + mt*16 + ln) * 256 + q*8;
        #pragma unroll
        for (int k0 = 0; k0 < 8; k0++) Af[mt][k0] = *(const sfrag8*)(ap + k0*32);
    }
    float bias[2][4];
    #pragma unroll
    for (int mt = 0; mt < 2; mt++)
        #pragma unroll
        for (int r = 0; r < 4; r++)
            bias[mt][r] = B3[m0 + wv*32 + mt*16 + q*4 + r];

    asm volatile("s_waitcnt vmcnt(0)" ::: "memory");
    __builtin_amdgcn_s_barrier();

    f32x4 acc[2][4];
    #pragma unroll
    for (int mt = 0; mt < 2; mt++)
        #pragma unroll
        for (int nt = 0; nt < 4; nt++)
            #pragma unroll
            for (int e = 0; e < 4; e++) acc[mt][nt][e] = 0.f;

    __builtin_amdgcn_s_setprio(1);
    #pragma unroll
    for (int k0 = 0; k0 < 8; k0++) {
        const int gg0 = ((k0*4 + q) ^ (ln & 7)) << 3;
        sfrag8 b0 = *(const sfrag8*)&xs[(0*16 + ln) * 256 + gg0];
        sfrag8 b1 = *(const sfrag8*)&xs[(1*16 + ln) * 256 + gg0];
        sfrag8 b2 = *(const sfrag8*)&xs[(2*16 + ln) * 256 + gg0];
        sfrag8 b3 = *(const sfrag8*)&xs[(3*16 + ln) * 256 + gg0];
        #pragma unroll
        for (int mt = 0; mt < 2; mt++) {
            acc[mt][0] = __builtin_amdgcn_mfma_f32_16x16x32_bf16(Af[mt][k0], b0, acc[mt][0], 0, 0, 0);
            acc[mt][1] = __builtin_amdgcn_mfma_f32_16x16x32_bf16(Af[mt][k0], b1, acc[mt][1], 0, 0, 0);
            acc[mt][2] = __builtin_amdgcn_mfma_f32_16x16x32_bf16(Af[mt][k0], b2, acc[mt][2], 0, 0, 0);
            acc[mt][3] = __builtin_amdgcn_mfma_f32_16x16x32_bf16(Af[mt][k0], b3, acc[mt][3], 0, 0, 0);
        }
    }
    __builtin_amdgcn_s_setprio(0);

    #pragma unroll
    for (int mt = 0; mt < 2; mt++)
        #pragma unroll
        for (int nt = 0; nt < 4; nt++)
            #pragma unroll
            for (int r = 0; r < 4; r++) {
                int row = m0 + wv*32 + mt*16 + q*4 + r;
                int col = l0 + nt*16 + ln;
                out[(size_t)row * LSEQ + col] = acc[mt][nt][r] + bias[mt][r];
            }
}

// ============ launch ============
extern "C" void kernel_launch(void* const* d_in, const int* in_sizes, int n_in,
                              void* d_out, int out_size, void* d_ws, size_t ws_size,
                              hipStream_t stream) {
    const float* x     = (const float*)d_in[0];
    const float* gn_w  = (const float*)d_in[1];
    const float* gn_b  = (const float*)d_in[2];
    const float* w_qkv = (const float*)d_in[3];
    const float* b_qkv = (const float*)d_in[4];
    const float* w_out = (const float*)d_in[5];
    const float* b_out = (const float*)d_in[6];
    float* out = (float*)d_out;
    float* ws  = (float*)d_ws;

    float*    gsum   = ws + 0;        // 32
    float*    gsumsq = ws + 32;       // 32   [memset covers 64 floats]
    float*    S      = ws + 64;       // 32768 [zeroed by k_fold]
    float*    Z      = ws + 32832;    // 512   [zeroed by k_fold]
    float*    BE     = ws + 33856;    // 1536
    float*    BE2    = ws + 35392;    // 1024
    ushort_t* WEB    = (ushort_t*)(ws + 36416);    // 1024*256 bf16 (65536 f)
    ushort_t* W3B    = (ushort_t*)(ws + 233024);   // 256*256 bf16 (32768 f)
    float*    B3     = ws + 265792;   // 256
    ushort_t* XT     = (ushort_t*)(ws + 266048);   // 32768*256 bf16 (4194304 f)

    hipMemsetAsync(ws, 0, 64 * sizeof(float), stream);   // gsum, gsumsq only
    k_tr    <<<512,  256, 0, stream>>>(x, XT, gsum, gsumsq);
    k_fold  <<<1536, 256, 0, stream>>>(gn_w, gn_b, gsum, gsumsq, w_qkv, b_qkv,
                                       WEB, BE, BE2, S, Z);
    k_attn  <<<512,  256, 0, stream>>>(XT, WEB, BE2, S, Z);
    k_w23   <<<256,  512, 0, stream>>>(w_out, S, Z, w_qkv, BE, gn_w, gsum, gsumsq,
                                       b_out, W3B, B3);
    k_final <<<1024, 256, 0, stream>>>(XT, W3B, B3, out);
}